// Round 16
// baseline (100.406 us; speedup 1.0000x reference)
//
#include <hip/hip_runtime.h>
#include <stdint.h>

#define NB     16
#define NANCH  65536
#define NC     21
#define NCLS   20
#define NCOL   (NB * NCLS)     // 320
#define TOPK   200
#define NBINS  1024
#define CAP    256
#define CAPCOL 4096            // global per-column candidate capacity
#define CAPLDS 2048            // LDS staging capacity (nc ~1150 @ TPRE=0.2)
#define CNTSTRIDE 16           // one counter per 64B cache line

constexpr float TH      = 0.05f;
constexpr float TPRE    = 0.20f;                  // pre-filter threshold
constexpr float SCALE20 = (float)NBINS / 0.80f;   // bins over [0.20, 1.0]
constexpr float SCALE05 = (float)NBINS / 0.95f;   // fallback bins [0.05, 1.0]

__device__ __forceinline__ int bin20(float s) {
  int b = (int)((s - 0.20f) * SCALE20);
  return b < 0 ? 0 : (b > NBINS - 1 ? NBINS - 1 : b);
}
__device__ __forceinline__ int bin05(float s) {
  int b = (int)((s - 0.05f) * SCALE05);
  return b < 0 ? 0 : (b > NBINS - 1 ? NBINS - 1 : b);
}

__device__ __forceinline__ unsigned long long shflx64(unsigned long long v, int m) {
  unsigned int lo = (unsigned int)v, hi = (unsigned int)(v >> 32);
  lo = __shfl_xor(lo, m);
  hi = __shfl_xor(hi, m);
  return ((unsigned long long)hi << 32) | lo;
}
// uniform-lane 64-bit readlane broadcast; lane index may be a uniform
// runtime value (SGPR) — keeps the greedy loop ROLLED and tiny.
__device__ __forceinline__ unsigned long long rl64(unsigned long long v, int lane) {
  unsigned int lo = __builtin_amdgcn_readlane((int)(unsigned int)v, lane);
  unsigned int hi = __builtin_amdgcn_readlane((int)(unsigned int)(v >> 32), lane);
  return ((unsigned long long)hi << 32) | lo;
}

// exact softmax tail (numpy pairwise sum for n=21)
__device__ __forceinline__ void softmax_tail(const float* x, float* e, float& S) {
  float m = x[0];
#pragma unroll
  for (int c = 1; c < NC; ++c) m = fmaxf(m, x[c]);
#pragma unroll
  for (int c = 0; c < NC; ++c) e[c] = expf(x[c] - m);
  float r0 = e[0] + e[8],  r1 = e[1] + e[9],  r2 = e[2] + e[10], r3 = e[3] + e[11];
  float r4 = e[4] + e[12], r5 = e[5] + e[13], r6 = e[6] + e[14], r7 = e[7] + e[15];
  S = ((r0 + r1) + (r2 + r3)) + ((r4 + r5) + (r6 + r7));
  S += e[16]; S += e[17]; S += e[18]; S += e[19]; S += e[20];
}

// ---------------- K1: softmax + candidate collection (ballot-aggregated) ----
__global__ __launch_bounds__(256) void softmax_collect_kernel(
    const float* __restrict__ conf,
    unsigned int* __restrict__ cnt, unsigned long long* __restrict__ cand) {
  const int tid = threadIdx.x;
  __shared__ float ld[256 * NC];          // rows at odd stride 21
  const float4* src = (const float4*)conf + (long long)blockIdx.x * 1344;
  float4* dst4 = (float4*)ld;
#pragma unroll
  for (int i = 0; i < 5; ++i) dst4[tid + i * 256] = src[tid + i * 256];
  if (tid < 64) dst4[tid + 1280] = src[tid + 1280];
  __syncthreads();

  const int a = blockIdx.x * 256 + tid;
  const int b = a >> 16;
  const int n = a & (NANCH - 1);
  float x[NC];
#pragma unroll
  for (int c = 0; c < NC; ++c) x[c] = ld[tid * NC + c];
  float e[NC], S;
  softmax_tail(x, e, S);
  const float t = TPRE * S;               // div-free take test
  unsigned int takemask = 0;
#pragma unroll
  for (int c = 0; c < NCLS; ++c)
    if (e[c + 1] >= t) takemask |= (1u << c);

  __shared__ unsigned int wcnt[4][NCLS];
  __shared__ unsigned int wbase[4][NCLS];
  const int wave = tid >> 6, lane = tid & 63;
#pragma unroll
  for (int c = 0; c < NCLS; ++c) {
    unsigned long long m = __ballot((takemask >> c) & 1);
    if (lane == 0) wcnt[wave][c] = (unsigned int)__popcll(m);
  }
  __syncthreads();
  if (tid < NCLS) {
    const int c = tid;
    unsigned int t0 = wcnt[0][c], t1 = wcnt[1][c], t2 = wcnt[2][c], t3 = wcnt[3][c];
    unsigned int tot = t0 + t1 + t2 + t3;
    unsigned int base = tot ? atomicAdd(&cnt[(b * NCLS + c) * CNTSTRIDE], tot) : 0u;
    wbase[0][c] = base;
    wbase[1][c] = base + t0;
    wbase[2][c] = base + t0 + t1;
    wbase[3][c] = base + t0 + t1 + t2;
  }
  __syncthreads();
#pragma unroll
  for (int c = 0; c < NCLS; ++c) {
    bool take = (takemask >> c) & 1;
    unsigned long long m = __ballot(take);
    if (take) {
      float s = e[c + 1] / S;             // IEEE div, like np — takers only
      unsigned int off = wbase[wave][c] +
                         (unsigned int)__popcll(m & ((1ULL << lane) - 1));
      if (off < CAPCOL) {
        unsigned int key = __float_as_uint(s) | 0x80000000u;  // s > 0
        cand[(long long)(b * NCLS + c) * CAPCOL + off] =
            ((unsigned long long)(key ^ 0xFFFFFFFFu) << 32) |
            (unsigned long long)(unsigned int)n;
      }
    }
  }
}

// ---------------- wave-0 parallel cut-bin finder (1024 bins in LDS) ---------
__device__ __forceinline__ int find_sel(unsigned int* hist, unsigned int* part,
                                        int* s_sel, int tid) {
  unsigned int p = hist[tid*4] + hist[tid*4+1] + hist[tid*4+2] + hist[tid*4+3];
  part[tid] = p;
  if (tid == 0) *s_sel = -1;
  __syncthreads();
  if (tid < 64) {
    unsigned int p4 = part[tid*4] + part[tid*4+1] + part[tid*4+2] + part[tid*4+3];
    unsigned int sfx = p4;                 // inclusive suffix over 64 groups
#pragma unroll
    for (int off = 1; off < 64; off <<= 1) {
      unsigned int o = __shfl_down(sfx, off);
      if (tid + off < 64) sfx += o;
    }
    unsigned int above = sfx - p4;
    if (above < TOPK && sfx >= TOPK) {     // exactly one owner (if total>=200)
      unsigned int cum = above; int sel = tid * 16; bool found = false;
      for (int q = 3; q >= 0 && !found; --q) {
        unsigned int pc = part[tid*4 + q];
        if (cum + pc >= TOPK) {
          for (int i = 3; i >= 0; --i) {
            unsigned int c = hist[(tid*4+q)*4 + i];
            if (cum + c >= TOPK) { sel = (tid*4+q)*4 + i; found = true; break; }
            cum += c;
          }
        } else cum += pc;
      }
      *s_sel = sel;
    }
  }
  __syncthreads();
  return *s_sel;
}

// ---------------- K3: per-column select + sort + decode + NMS + output ------
__global__ __launch_bounds__(256) void topk_nms_kernel(
    const unsigned long long* __restrict__ candg,
    const unsigned int* __restrict__ cnt,
    const float* __restrict__ conf, const float* __restrict__ loc,
    const float* __restrict__ anchors, float* __restrict__ out) {
  const int bc = blockIdx.x;
  const int b  = bc / NCLS;
  const int cls = bc % NCLS;
  const int tid = threadIdx.x;

  __shared__ unsigned long long cg_lds[CAPLDS];   // 16 KB
  __shared__ unsigned int hist[NBINS];
  __shared__ unsigned int part[256];
  __shared__ int s_sel, s_n;
  __shared__ unsigned long long cand[CAP];
  __shared__ float4 box4[TOPK];                   // x1,y1,x2,y2 (b128 reads)
  __shared__ float sscore[TOPK];
  __shared__ unsigned long long adj[TOPK][4];
  __shared__ unsigned long long keptw[4];

  int nc = (int)cnt[bc * CNTSTRIDE];
  const bool fast = (nc >= TOPK && nc <= CAPLDS);
  for (int i = tid; i < NBINS; i += 256) hist[i] = 0;
  if (tid == 0) s_n = 0;

  const unsigned long long* cg = candg + (long long)bc * CAPCOL;
  if (fast) {
    // prefetch all candidates into LDS (vectorized, back-to-back)
    const int npair = nc >> 1;
    const ulonglong2* cg2 = (const ulonglong2*)cg;
    for (int i = tid; i < npair; i += 256) {
      ulonglong2 v2 = cg2[i];
      cg_lds[2 * i]     = v2.x;
      cg_lds[2 * i + 1] = v2.y;
    }
    if ((nc & 1) && tid == 0) cg_lds[nc - 1] = cg[nc - 1];
    __syncthreads();
    for (int i = tid; i < nc; i += 256) {
      unsigned int key = (unsigned int)(cg_lds[i] >> 32) ^ 0xFFFFFFFFu;
      float s = __uint_as_float(key ^ 0x80000000u);
      atomicAdd(&hist[bin20(s)], 1u);
    }
    __syncthreads();
    int sel = find_sel(hist, part, &s_sel, tid);
    for (int i = tid; i < nc; i += 256) {
      unsigned long long k64 = cg_lds[i];
      unsigned int key = (unsigned int)(k64 >> 32) ^ 0xFFFFFFFFu;
      float s = __uint_as_float(key ^ 0x80000000u);
      if (bin20(s) >= sel) {
        int pos = atomicAdd(&s_n, 1);
        if (pos < CAP) cand[pos] = k64;
      }
    }
  } else {
    __syncthreads();
    // fallback: full-column recompute from conf, bins over [0.05, 1]
    for (int n = tid; n < NANCH; n += 256) {
      const float* row = conf + ((long long)b * NANCH + n) * NC;
      float x[NC], e[NC], S;
#pragma unroll
      for (int c = 0; c < NC; ++c) x[c] = row[c];
      softmax_tail(x, e, S);
      float s = e[cls + 1] / S;
      if (s >= TH) atomicAdd(&hist[bin05(s)], 1u);
    }
    __syncthreads();
    int sel = find_sel(hist, part, &s_sel, tid);
    for (int n = tid; n < NANCH; n += 256) {
      const float* row = conf + ((long long)b * NANCH + n) * NC;
      float x[NC], e[NC], S;
#pragma unroll
      for (int c = 0; c < NC; ++c) x[c] = row[c];
      softmax_tail(x, e, S);
      float s = e[cls + 1] / S;
      if (s >= TH && (sel < 0 || bin05(s) >= sel)) {
        int pos = atomicAdd(&s_n, 1);
        if (pos < CAP) {
          unsigned int key = __float_as_uint(s) | 0x80000000u;
          cand[pos] = ((unsigned long long)(key ^ 0xFFFFFFFFu) << 32) |
                      (unsigned long long)(unsigned int)n;
        }
      }
    }
  }
  __syncthreads();
  int ncand = s_n; if (ncand > CAP) ncand = CAP;

  // hybrid bitonic sort: register element, shfl_xor for j<=32, LDS for j>=64.
  // ascending u64 = (score desc, idx asc) — exact lax.top_k tie semantics.
  unsigned long long v = (tid < ncand) ? cand[tid] : ~0ULL;
  for (int k = 2; k <= CAP; k <<= 1) {
    const bool up = ((tid & k) == 0);
    for (int j = k >> 1; j >= 64; j >>= 1) {
      cand[tid] = v;
      __syncthreads();
      unsigned long long o = cand[tid ^ j];
      bool keepMin = (((tid & j) == 0) == up);
      v = ((v < o) == keepMin) ? v : o;
      __syncthreads();
    }
    for (int j = (k >> 1) < 32 ? (k >> 1) : 32; j >= 1; j >>= 1) {
      unsigned long long o = shflx64(v, j);
      bool keepMin = (((tid & j) == 0) == up);
      v = ((v < o) == keepMin) ? v : o;
    }
  }
  const int nsel = (ncand < TOPK) ? ncand : TOPK;

  // gather + decode (exact reference op order); thread tid holds rank tid
  if (tid < TOPK) {
    if (tid < nsel) {
      unsigned int key = (unsigned int)(v >> 32) ^ 0xFFFFFFFFu;
      float s = __uint_as_float(key ^ 0x80000000u);
      int idx = (int)(unsigned int)(v & 0xFFFFFFFFu);
      float4 anc = ((const float4*)anchors)[idx];
      float4 l   = ((const float4*)loc)[(long long)b * NANCH + idx];
      float cx = anc.x + (l.x * 0.1f) * anc.z;
      float cy = anc.y + (l.y * 0.1f) * anc.w;
      float w  = anc.z * expf(l.z * 0.2f);
      float h  = anc.w * expf(l.w * 0.2f);
      box4[tid] = make_float4(cx - 0.5f * w, cy - 0.5f * h,
                              cx + 0.5f * w, cy + 0.5f * h);
      sscore[tid] = s;
    } else {
      box4[tid] = make_float4(0.f, 0.f, 0.f, 0.f);
      sscore[tid] = 0.0f;
    }
  }
  __syncthreads();

  // IoU row per thread. ROLLED outer word loop + unroll-4 inner: body ~1KB,
  // I-cache resident (R13-R15's fully-unrolled tails were ~30KB straight-line
  // code -> I-fetch-bound at 1 wave/SIMD). 4 b128 reads still batch per wait.
  if (tid < TOPK) {
    const float4 a4 = box4[tid];
    const float aar = fmaxf(a4.z - a4.x, 0.f) * fmaxf(a4.w - a4.y, 0.f);
    const int myw = tid >> 6, myb = tid & 63;
#pragma unroll 1
    for (int w = 0; w < 4; ++w) {
      const int jend = (w < 3) ? 64 : (TOPK - 192);   // 64,64,64,8
      unsigned long long roww = 0;
#pragma unroll 4
      for (int jj = 0; jj < jend; ++jj) {
        const int j = (w << 6) + jj;
        float4 b4 = box4[j];                           // ds_read_b128
        float jar = fmaxf(b4.z - b4.x, 0.f) * fmaxf(b4.w - b4.y, 0.f);
        float ltx = fmaxf(a4.x, b4.x);
        float lty = fmaxf(a4.y, b4.y);
        float rbx = fminf(a4.z, b4.z);
        float rby = fminf(a4.w, b4.w);
        float iw = fmaxf(rbx - ltx, 0.0f);
        float ih = fmaxf(rby - lty, 0.0f);
        float inter = iw * ih;
        float uni = aar + jar - inter;
        float um = fmaxf(uni, 1e-9f);
        float half = 0.5f * um;
        bool hit;
        if (inter > half * 1.000001f)      hit = true;
        else if (inter < half * 0.999999f) hit = false;
        else                               hit = (inter / um > 0.5f);  // rare
        roww |= (unsigned long long)(hit ? 1u : 0u) << jj;
      }
      unsigned long long tri = (w < myw) ? 0ULL
                             : (w > myw) ? ~0ULL
                             : ((myb == 63) ? 0ULL : (~0ULL << (myb + 1)));
      adj[tid][w] = roww & tri;                        // upper triangle only
    }
  }
  __syncthreads();

  // wave-0 branchless register greedy. ROLLED loops (#pragma unroll 1):
  // body ~20 insts looped — stays in L1I; readlane takes the SGPR counter.
  if (tid < 64) {
    const int l = tid;
    unsigned long long r0[4], r1[4], r2[4], r3[4];
#pragma unroll
    for (int w = 0; w < 4; ++w) {
      r0[w] = adj[l][w];
      r1[w] = adj[l + 64][w];
      r2[w] = adj[l + 128][w];
      r3[w] = (l < 8) ? adj[l + 192][w] : 0ULL;   // rows 192..199
    }
    unsigned long long sup0 = 0, sup1 = 0, sup2 = 0, sup3 = 0;
    unsigned long long k0 = 0, k1 = 0, k2 = 0, k3 = 0;
#pragma unroll 1
    for (int ii = 0; ii < 64; ++ii) {                       // rows 0..63
      unsigned long long live = ((~sup0 >> ii) & 1ULL) &
                                (unsigned long long)(ii < nsel);
      unsigned long long mask = 0ULL - live;
      k0 |= live << ii;
      sup0 |= rl64(r0[0], ii) & mask; sup1 |= rl64(r0[1], ii) & mask;
      sup2 |= rl64(r0[2], ii) & mask; sup3 |= rl64(r0[3], ii) & mask;
    }
#pragma unroll 1
    for (int ii = 0; ii < 64; ++ii) {                       // rows 64..127
      unsigned long long live = ((~sup1 >> ii) & 1ULL) &
                                (unsigned long long)((64 + ii) < nsel);
      unsigned long long mask = 0ULL - live;
      k1 |= live << ii;
      sup1 |= rl64(r1[1], ii) & mask; sup2 |= rl64(r1[2], ii) & mask;
      sup3 |= rl64(r1[3], ii) & mask;
    }
#pragma unroll 1
    for (int ii = 0; ii < 64; ++ii) {                       // rows 128..191
      unsigned long long live = ((~sup2 >> ii) & 1ULL) &
                                (unsigned long long)((128 + ii) < nsel);
      unsigned long long mask = 0ULL - live;
      k2 |= live << ii;
      sup2 |= rl64(r2[2], ii) & mask; sup3 |= rl64(r2[3], ii) & mask;
    }
#pragma unroll 1
    for (int ii = 0; ii < 8; ++ii) {                        // rows 192..199
      unsigned long long live = ((~sup3 >> ii) & 1ULL) &
                                (unsigned long long)((192 + ii) < nsel);
      unsigned long long mask = 0ULL - live;
      k3 |= live << ii;
      sup3 |= rl64(r3[3], ii) & mask;
    }
    if (l == 0) { keptw[0] = k0; keptw[1] = k1; keptw[2] = k2; keptw[3] = k3; }
  }
  __syncthreads();

  // coalesced output: out[bc*1000 + pos], 4 rounds of 256 lanes
  const float* fb = (const float*)box4;     // [200*4]
  float* ob = out + (long long)bc * (TOPK * 5);
  for (int pos = tid; pos < TOPK * 5; pos += 256) {
    int row = pos / 5;                       // const-div -> mul_hi
    int k5  = pos - row * 5;
    bool kp = (keptw[row >> 6] >> (row & 63)) & 1ULL;
    float val = (k5 == 4) ? sscore[row] : fb[row * 4 + k5];
    ob[pos] = kp ? val : 0.0f;
  }
}

extern "C" void kernel_launch(void* const* d_in, const int* in_sizes, int n_in,
                              void* d_out, int out_size, void* d_ws, size_t ws_size,
                              hipStream_t stream) {
  const float* conf    = (const float*)d_in[0];
  const float* loc     = (const float*)d_in[1];
  const float* anchors = (const float*)d_in[2];
  float* out = (float*)d_out;

  // ws layout: cand 320*4096*8 = 10,485,760 B ; cnt 320*16*4 = 20,480 B
  char* ws = (char*)d_ws;
  unsigned long long* cand = (unsigned long long*)ws;
  unsigned int*       cnt  = (unsigned int*)(ws + 10485760);

  hipMemsetAsync(ws + 10485760, 0, 320 * CNTSTRIDE * 4, stream);  // zero cnt
  softmax_collect_kernel<<<(NB * NANCH) / 256, 256, 0, stream>>>(conf, cnt, cand);
  topk_nms_kernel<<<NCOL, 256, 0, stream>>>(cand, cnt, conf, loc, anchors, out);
}

// Round 17
// 91.620 us; speedup vs baseline: 1.0959x; 1.0959x over previous
//
#include <hip/hip_runtime.h>
#include <stdint.h>

#define NB     16
#define NANCH  65536
#define NC     21
#define NCLS   20
#define NCOL   (NB * NCLS)     // 320
#define TOPK   200
#define NBINS  1024
#define CAP    256
#define CAPCOL 4096            // global per-column candidate capacity
#define CAPLDS 2048            // LDS staging capacity (nc ~1150 @ TPRE=0.2)
#define CNTSTRIDE 16           // one counter per 64B cache line

constexpr float TH      = 0.05f;
constexpr float TPRE    = 0.20f;                  // pre-filter threshold
constexpr float SCALE20 = (float)NBINS / 0.80f;   // bins over [0.20, 1.0]
constexpr float SCALE05 = (float)NBINS / 0.95f;   // fallback bins [0.05, 1.0]

__device__ __forceinline__ int bin20(float s) {
  int b = (int)((s - 0.20f) * SCALE20);
  return b < 0 ? 0 : (b > NBINS - 1 ? NBINS - 1 : b);
}
__device__ __forceinline__ int bin05(float s) {
  int b = (int)((s - 0.05f) * SCALE05);
  return b < 0 ? 0 : (b > NBINS - 1 ? NBINS - 1 : b);
}

__device__ __forceinline__ unsigned long long shflx64(unsigned long long v, int m) {
  unsigned int lo = (unsigned int)v, hi = (unsigned int)(v >> 32);
  lo = __shfl_xor(lo, m);
  hi = __shfl_xor(hi, m);
  return ((unsigned long long)hi << 32) | lo;
}
// uniform-lane 64-bit readlane broadcast (SGPR chain, rolled-loop friendly)
__device__ __forceinline__ unsigned long long rl64(unsigned long long v, int lane) {
  unsigned int lo = __builtin_amdgcn_readlane((int)(unsigned int)v, lane);
  unsigned int hi = __builtin_amdgcn_readlane((int)(unsigned int)(v >> 32), lane);
  return ((unsigned long long)hi << 32) | lo;
}

// exact softmax tail (numpy pairwise sum for n=21)
__device__ __forceinline__ void softmax_tail(const float* x, float* e, float& S) {
  float m = x[0];
#pragma unroll
  for (int c = 1; c < NC; ++c) m = fmaxf(m, x[c]);
#pragma unroll
  for (int c = 0; c < NC; ++c) e[c] = expf(x[c] - m);
  float r0 = e[0] + e[8],  r1 = e[1] + e[9],  r2 = e[2] + e[10], r3 = e[3] + e[11];
  float r4 = e[4] + e[12], r5 = e[5] + e[13], r6 = e[6] + e[14], r7 = e[7] + e[15];
  S = ((r0 + r1) + (r2 + r3)) + ((r4 + r5) + (r6 + r7));
  S += e[16]; S += e[17]; S += e[18]; S += e[19]; S += e[20];
}

// ---------------- K1: softmax + candidate collection (ballot-aggregated) ----
__global__ __launch_bounds__(256) void softmax_collect_kernel(
    const float* __restrict__ conf,
    unsigned int* __restrict__ cnt, unsigned long long* __restrict__ cand) {
  const int tid = threadIdx.x;
  __shared__ float ld[256 * NC];          // rows at odd stride 21
  const float4* src = (const float4*)conf + (long long)blockIdx.x * 1344;
  float4* dst4 = (float4*)ld;
#pragma unroll
  for (int i = 0; i < 5; ++i) dst4[tid + i * 256] = src[tid + i * 256];
  if (tid < 64) dst4[tid + 1280] = src[tid + 1280];
  __syncthreads();

  const int a = blockIdx.x * 256 + tid;
  const int b = a >> 16;
  const int n = a & (NANCH - 1);
  float x[NC];
#pragma unroll
  for (int c = 0; c < NC; ++c) x[c] = ld[tid * NC + c];
  float e[NC], S;
  softmax_tail(x, e, S);
  const float t = TPRE * S;               // div-free take test
  unsigned int takemask = 0;
#pragma unroll
  for (int c = 0; c < NCLS; ++c)
    if (e[c + 1] >= t) takemask |= (1u << c);

  __shared__ unsigned int wcnt[4][NCLS];
  __shared__ unsigned int wbase[4][NCLS];
  const int wave = tid >> 6, lane = tid & 63;
#pragma unroll
  for (int c = 0; c < NCLS; ++c) {
    unsigned long long m = __ballot((takemask >> c) & 1);
    if (lane == 0) wcnt[wave][c] = (unsigned int)__popcll(m);
  }
  __syncthreads();
  if (tid < NCLS) {
    const int c = tid;
    unsigned int t0 = wcnt[0][c], t1 = wcnt[1][c], t2 = wcnt[2][c], t3 = wcnt[3][c];
    unsigned int tot = t0 + t1 + t2 + t3;
    unsigned int base = tot ? atomicAdd(&cnt[(b * NCLS + c) * CNTSTRIDE], tot) : 0u;
    wbase[0][c] = base;
    wbase[1][c] = base + t0;
    wbase[2][c] = base + t0 + t1;
    wbase[3][c] = base + t0 + t1 + t2;
  }
  __syncthreads();
#pragma unroll
  for (int c = 0; c < NCLS; ++c) {
    bool take = (takemask >> c) & 1;
    unsigned long long m = __ballot(take);
    if (take) {
      float s = e[c + 1] / S;             // IEEE div, like np — takers only
      unsigned int off = wbase[wave][c] +
                         (unsigned int)__popcll(m & ((1ULL << lane) - 1));
      if (off < CAPCOL) {
        unsigned int key = __float_as_uint(s) | 0x80000000u;  // s > 0
        cand[(long long)(b * NCLS + c) * CAPCOL + off] =
            ((unsigned long long)(key ^ 0xFFFFFFFFu) << 32) |
            (unsigned long long)(unsigned int)n;
      }
    }
  }
}

// ---------------- K3: 1024 threads/column — select+sort+decode+NMS+output ---
// 16 waves/block = 4 waves/SIMD (latency hiding); 33.5 KB LDS + 52 VGPR lets
// 2 blocks co-reside per CU -> 320 blocks in ONE scheduling round.
__global__ __launch_bounds__(1024) void topk_nms_kernel(
    const unsigned long long* __restrict__ candg,
    const unsigned int* __restrict__ cnt,
    const float* __restrict__ conf, const float* __restrict__ loc,
    const float* __restrict__ anchors, float* __restrict__ out) {
  const int bc = blockIdx.x;
  const int b  = bc / NCLS;
  const int cls = bc % NCLS;
  const int tid = threadIdx.x;

  __shared__ unsigned long long cg_lds[CAPLDS];   // 16 KB
  __shared__ unsigned int hist[NBINS];            // 4 KB
  __shared__ unsigned int part[256];              // 1 KB
  __shared__ int s_sel, s_n;
  __shared__ unsigned long long cand[CAP];        // 2 KB
  __shared__ float4 box4[TOPK];                   // 3.2 KB
  __shared__ float sscore[TOPK];                  // 0.8 KB
  __shared__ unsigned long long adj[TOPK][4];     // 6.4 KB
  __shared__ unsigned long long keptw[4];

  int nc = (int)cnt[bc * CNTSTRIDE];
  const bool fast = (nc >= TOPK && nc <= CAPLDS);
  for (int i = tid; i < NBINS; i += 1024) hist[i] = 0;
  if (tid == 0) s_n = 0;
  __syncthreads();                                 // (A) hist zeroed

  const unsigned long long* cg = candg + (long long)bc * CAPCOL;
  if (fast) {
    // prefetch all candidates into LDS (1024-wide, single latency window)
    const int npair = nc >> 1;
    const ulonglong2* cg2 = (const ulonglong2*)cg;
    for (int i = tid; i < npair; i += 1024) {
      ulonglong2 v2 = cg2[i];
      cg_lds[2 * i]     = v2.x;
      cg_lds[2 * i + 1] = v2.y;
    }
    if ((nc & 1) && tid == 0) cg_lds[nc - 1] = cg[nc - 1];
  }
  __syncthreads();                                 // (B) prefetch visible

  if (fast) {
    for (int i = tid; i < nc; i += 1024) {
      unsigned int key = (unsigned int)(cg_lds[i] >> 32) ^ 0xFFFFFFFFu;
      float s = __uint_as_float(key ^ 0x80000000u);
      atomicAdd(&hist[bin20(s)], 1u);
    }
  } else {
    for (int n = tid; n < NANCH; n += 1024) {
      const float* row = conf + ((long long)b * NANCH + n) * NC;
      float x[NC], e[NC], S;
#pragma unroll
      for (int c = 0; c < NC; ++c) x[c] = row[c];
      softmax_tail(x, e, S);
      float s = e[cls + 1] / S;
      if (s >= TH) atomicAdd(&hist[bin05(s)], 1u);
    }
  }
  __syncthreads();                                 // (C) hist built

  // ---- cut-bin finder (wave 0 scans; all threads share barriers) ----
  if (tid < 256)
    part[tid] = hist[tid*4] + hist[tid*4+1] + hist[tid*4+2] + hist[tid*4+3];
  if (tid == 0) s_sel = -1;
  __syncthreads();                                 // (D)
  if (tid < 64) {
    unsigned int p4 = part[tid*4] + part[tid*4+1] + part[tid*4+2] + part[tid*4+3];
    unsigned int sfx = p4;                 // inclusive suffix over 64 groups
#pragma unroll
    for (int off = 1; off < 64; off <<= 1) {
      unsigned int o = __shfl_down(sfx, off);
      if (tid + off < 64) sfx += o;
    }
    unsigned int above = sfx - p4;
    if (above < TOPK && sfx >= TOPK) {     // exactly one owner (if total>=200)
      unsigned int cum = above; int sel = tid * 16; bool found = false;
      for (int q = 3; q >= 0 && !found; --q) {
        unsigned int pc = part[tid*4 + q];
        if (cum + pc >= TOPK) {
          for (int i = 3; i >= 0; --i) {
            unsigned int c = hist[(tid*4+q)*4 + i];
            if (cum + c >= TOPK) { sel = (tid*4+q)*4 + i; found = true; break; }
            cum += c;
          }
        } else cum += pc;
      }
      s_sel = sel;
    }
  }
  __syncthreads();                                 // (E)
  const int sel = s_sel;

  if (fast) {
    for (int i = tid; i < nc; i += 1024) {
      unsigned long long k64 = cg_lds[i];
      unsigned int key = (unsigned int)(k64 >> 32) ^ 0xFFFFFFFFu;
      float s = __uint_as_float(key ^ 0x80000000u);
      if (bin20(s) >= sel) {
        int pos = atomicAdd(&s_n, 1);
        if (pos < CAP) cand[pos] = k64;
      }
    }
  } else {
    for (int n = tid; n < NANCH; n += 1024) {
      const float* row = conf + ((long long)b * NANCH + n) * NC;
      float x[NC], e[NC], S;
#pragma unroll
      for (int c = 0; c < NC; ++c) x[c] = row[c];
      softmax_tail(x, e, S);
      float s = e[cls + 1] / S;
      if (s >= TH && (sel < 0 || bin05(s) >= sel)) {
        int pos = atomicAdd(&s_n, 1);
        if (pos < CAP) {
          unsigned int key = __float_as_uint(s) | 0x80000000u;
          cand[pos] = ((unsigned long long)(key ^ 0xFFFFFFFFu) << 32) |
                      (unsigned long long)(unsigned int)n;
        }
      }
    }
  }
  __syncthreads();                                 // (F) cand ready
  int ncand = s_n; if (ncand > CAP) ncand = CAP;

  // hybrid bitonic sort on 256 elements (tid<256 hold them); barriers are
  // block-uniform. ascending u64 = (score desc, idx asc) — lax.top_k ties.
  unsigned long long v = (tid < ncand) ? cand[tid] : ~0ULL;
  for (int k = 2; k <= CAP; k <<= 1) {
    const bool up = ((tid & k) == 0);
    for (int j = k >> 1; j >= 64; j >>= 1) {
      if (tid < 256) cand[tid] = v;
      __syncthreads();
      if (tid < 256) {
        unsigned long long o = cand[tid ^ j];
        bool keepMin = (((tid & j) == 0) == up);
        v = ((v < o) == keepMin) ? v : o;
      }
      __syncthreads();
    }
    if (tid < 256) {
      for (int j = (k >> 1) < 32 ? (k >> 1) : 32; j >= 1; j >>= 1) {
        unsigned long long o = shflx64(v, j);
        bool keepMin = (((tid & j) == 0) == up);
        v = ((v < o) == keepMin) ? v : o;
      }
    }
  }
  const int nsel = (ncand < TOPK) ? ncand : TOPK;

  // gather + decode (exact reference op order); thread tid holds rank tid
  if (tid < TOPK) {
    if (tid < nsel) {
      unsigned int key = (unsigned int)(v >> 32) ^ 0xFFFFFFFFu;
      float s = __uint_as_float(key ^ 0x80000000u);
      int idx = (int)(unsigned int)(v & 0xFFFFFFFFu);
      float4 anc = ((const float4*)anchors)[idx];
      float4 l   = ((const float4*)loc)[(long long)b * NANCH + idx];
      float cx = anc.x + (l.x * 0.1f) * anc.z;
      float cy = anc.y + (l.y * 0.1f) * anc.w;
      float w  = anc.z * expf(l.z * 0.2f);
      float h  = anc.w * expf(l.w * 0.2f);
      box4[tid] = make_float4(cx - 0.5f * w, cy - 0.5f * h,
                              cx + 0.5f * w, cy + 0.5f * h);
      sscore[tid] = s;
    } else {
      box4[tid] = make_float4(0.f, 0.f, 0.f, 0.f);
      sscore[tid] = 0.0f;
    }
  }
  __syncthreads();                                 // (G) boxes ready

  // IoU: 800 independent (row, word) tasks — thread tid<800 computes
  // adj[tid>>2][tid&3]. Within a wave only 4 distinct box4[j] addresses per
  // read -> LDS broadcast; 4 waves/SIMD hide latency across rows.
  if (tid < TOPK * 4) {
    const int row = tid >> 2, w = tid & 3;
    const float4 a4 = box4[row];
    const float aar = fmaxf(a4.z - a4.x, 0.f) * fmaxf(a4.w - a4.y, 0.f);
    const int jend = (w < 3) ? 64 : (TOPK - 192);   // 64,64,64,8
    unsigned long long roww = 0;
#pragma unroll 4
    for (int jj = 0; jj < jend; ++jj) {
      const int j = (w << 6) + jj;
      float4 b4 = box4[j];                           // broadcast read
      float jar = fmaxf(b4.z - b4.x, 0.f) * fmaxf(b4.w - b4.y, 0.f);
      float ltx = fmaxf(a4.x, b4.x);
      float lty = fmaxf(a4.y, b4.y);
      float rbx = fminf(a4.z, b4.z);
      float rby = fminf(a4.w, b4.w);
      float iw = fmaxf(rbx - ltx, 0.0f);
      float ih = fmaxf(rby - lty, 0.0f);
      float inter = iw * ih;
      float uni = aar + jar - inter;
      float um = fmaxf(uni, 1e-9f);
      float half = 0.5f * um;
      bool hit;
      if (inter > half * 1.000001f)      hit = true;
      else if (inter < half * 0.999999f) hit = false;
      else                               hit = (inter / um > 0.5f);  // rare
      roww |= (unsigned long long)(hit ? 1u : 0u) << jj;
    }
    const int myw = row >> 6, myb = row & 63;
    unsigned long long tri = (w < myw) ? 0ULL
                           : (w > myw) ? ~0ULL
                           : ((myb == 63) ? 0ULL : (~0ULL << (myb + 1)));
    adj[row][w] = roww & tri;                        // upper triangle only
  }
  __syncthreads();                                 // (H) adjacency ready

  // wave-0 branchless register greedy (rolled; SALU chain via readlane)
  if (tid < 64) {
    const int l = tid;
    unsigned long long r0[4], r1[4], r2[4], r3[4];
#pragma unroll
    for (int w = 0; w < 4; ++w) {
      r0[w] = adj[l][w];
      r1[w] = adj[l + 64][w];
      r2[w] = adj[l + 128][w];
      r3[w] = (l < 8) ? adj[l + 192][w] : 0ULL;   // rows 192..199
    }
    unsigned long long sup0 = 0, sup1 = 0, sup2 = 0, sup3 = 0;
    unsigned long long k0 = 0, k1 = 0, k2 = 0, k3 = 0;
#pragma unroll 1
    for (int ii = 0; ii < 64; ++ii) {                       // rows 0..63
      unsigned long long live = ((~sup0 >> ii) & 1ULL) &
                                (unsigned long long)(ii < nsel);
      unsigned long long mask = 0ULL - live;
      k0 |= live << ii;
      sup0 |= rl64(r0[0], ii) & mask; sup1 |= rl64(r0[1], ii) & mask;
      sup2 |= rl64(r0[2], ii) & mask; sup3 |= rl64(r0[3], ii) & mask;
    }
#pragma unroll 1
    for (int ii = 0; ii < 64; ++ii) {                       // rows 64..127
      unsigned long long live = ((~sup1 >> ii) & 1ULL) &
                                (unsigned long long)((64 + ii) < nsel);
      unsigned long long mask = 0ULL - live;
      k1 |= live << ii;
      sup1 |= rl64(r1[1], ii) & mask; sup2 |= rl64(r1[2], ii) & mask;
      sup3 |= rl64(r1[3], ii) & mask;
    }
#pragma unroll 1
    for (int ii = 0; ii < 64; ++ii) {                       // rows 128..191
      unsigned long long live = ((~sup2 >> ii) & 1ULL) &
                                (unsigned long long)((128 + ii) < nsel);
      unsigned long long mask = 0ULL - live;
      k2 |= live << ii;
      sup2 |= rl64(r2[2], ii) & mask; sup3 |= rl64(r2[3], ii) & mask;
    }
#pragma unroll 1
    for (int ii = 0; ii < 8; ++ii) {                        // rows 192..199
      unsigned long long live = ((~sup3 >> ii) & 1ULL) &
                                (unsigned long long)((192 + ii) < nsel);
      unsigned long long mask = 0ULL - live;
      k3 |= live << ii;
      sup3 |= rl64(r3[3], ii) & mask;
    }
    if (l == 0) { keptw[0] = k0; keptw[1] = k1; keptw[2] = k2; keptw[3] = k3; }
  }
  __syncthreads();                                 // (I) keep mask ready

  // coalesced output: 1000 floats, single 1024-wide round
  const float* fb = (const float*)box4;     // [200*4]
  float* ob = out + (long long)bc * (TOPK * 5);
  for (int pos = tid; pos < TOPK * 5; pos += 1024) {
    int row = pos / 5;                       // const-div -> mul_hi
    int k5  = pos - row * 5;
    bool kp = (keptw[row >> 6] >> (row & 63)) & 1ULL;
    float val = (k5 == 4) ? sscore[row] : fb[row * 4 + k5];
    ob[pos] = kp ? val : 0.0f;
  }
}

extern "C" void kernel_launch(void* const* d_in, const int* in_sizes, int n_in,
                              void* d_out, int out_size, void* d_ws, size_t ws_size,
                              hipStream_t stream) {
  const float* conf    = (const float*)d_in[0];
  const float* loc     = (const float*)d_in[1];
  const float* anchors = (const float*)d_in[2];
  float* out = (float*)d_out;

  // ws layout: cand 320*4096*8 = 10,485,760 B ; cnt 320*16*4 = 20,480 B
  char* ws = (char*)d_ws;
  unsigned long long* cand = (unsigned long long*)ws;
  unsigned int*       cnt  = (unsigned int*)(ws + 10485760);

  hipMemsetAsync(ws + 10485760, 0, 320 * CNTSTRIDE * 4, stream);  // zero cnt
  softmax_collect_kernel<<<(NB * NANCH) / 256, 256, 0, stream>>>(conf, cnt, cand);
  topk_nms_kernel<<<NCOL, 1024, 0, stream>>>(cand, cnt, conf, loc, anchors, out);
}